// Round 2
// 1715.224 us; speedup vs baseline: 1.8041x; 1.8041x over previous
//
#include <hip/hip_runtime.h>
#include <hip/hip_bf16.h>

// Problem constants: B=4, S=2048, D=1024, H=16, DEPTH=64
#define SB 4
#define SS 2048
#define SD 1024
#define SH 16
#define DPT 64

typedef __attribute__((ext_vector_type(8))) short short8;   // 8 bf16 (4 VGPRs)
typedef __attribute__((ext_vector_type(4))) float f32x4;

__device__ inline f32x4 mfma16(short8 a, short8 b, f32x4 c) {
    return __builtin_amdgcn_mfma_f32_16x16x32_bf16(a, b, c, 0, 0, 0);
}

__device__ inline unsigned short f2bf(float x) {
    __hip_bfloat16 h = __float2bfloat16(x);
    return __builtin_bit_cast(unsigned short, h);
}

// ---------------------------------------------------------------------------
// Prep 1: fp32 -> bf16 cast (8,388,608 elements, exact coverage)
__global__ __launch_bounds__(256) void cast_k(const float* __restrict__ src,
                                              unsigned short* __restrict__ dst) {
    int i = (blockIdx.x * 256 + threadIdx.x) * 4;
    float4 v = *(const float4*)(src + i);
    ushort4 o;
    o.x = f2bf(v.x); o.y = f2bf(v.y); o.z = f2bf(v.z); o.w = f2bf(v.w);
    *(ushort4*)(dst + i) = o;
}

// ---------------------------------------------------------------------------
// Prep 2: W [K][N] fp32 -> Wt [N][K] bf16  (1024x1024)
__global__ __launch_bounds__(256) void wtrans_k(const float* __restrict__ W,
                                                unsigned short* __restrict__ Wt) {
    __shared__ float t[32][33];
    int tx = threadIdx.x & 31, ty = threadIdx.x >> 5;  // 32x8
    int n0 = blockIdx.x * 32, k0 = blockIdx.y * 32;
#pragma unroll
    for (int i = 0; i < 4; i++)
        t[ty + i * 8][tx] = W[(size_t)(k0 + ty + i * 8) * SD + n0 + tx];
    __syncthreads();
#pragma unroll
    for (int i = 0; i < 4; i++)
        Wt[(size_t)(n0 + ty + i * 8) * SD + k0 + tx] = f2bf(t[tx][ty + i * 8]);
}

// ---------------------------------------------------------------------------
// Prep 3: v [B,H,S,64] -> vt [B,H,64,S] (bf16 transpose per head)
__global__ __launch_bounds__(256) void vtrans_k(const unsigned short* __restrict__ v,
                                                unsigned short* __restrict__ vt) {
    __shared__ unsigned short t[32][34];
    int tx = threadIdx.x & 31, ty = threadIdx.x >> 5;
    int d0 = blockIdx.x * 32, s0 = blockIdx.y * 32, bh = blockIdx.z;
    const unsigned short* src = v + (size_t)bh * SS * DPT;
    unsigned short* dst = vt + (size_t)bh * DPT * SS;
#pragma unroll
    for (int i = 0; i < 4; i++)
        t[ty + i * 8][tx] = src[(size_t)(s0 + ty + i * 8) * DPT + d0 + tx];
    __syncthreads();
#pragma unroll
    for (int i = 0; i < 4; i++)
        dst[(size_t)(d0 + ty + i * 8) * SS + s0 + tx] = t[tx][ty + i * 8];
}

// ---------------------------------------------------------------------------
// Prep 4: Mask fp32 {0,1} [B,1,S,S] -> bit-packed (1 bit per element, 2 MB).
// Wave-coalesced dword reads; __ballot yields 64 cols -> 2 words.
__global__ __launch_bounds__(256) void maskbits_k(const float* __restrict__ Mask,
                                                  unsigned int* __restrict__ bits) {
    size_t i = (size_t)blockIdx.x * 256 + threadIdx.x;
    float v = Mask[i];
    unsigned long long m = __ballot(v != 0.f);
    int lane = threadIdx.x & 63;
    if (lane == 0)
        bits[i >> 5] = (unsigned int)m;
    else if (lane == 32)
        bits[i >> 5] = (unsigned int)(m >> 32);
}

// ---------------------------------------------------------------------------
// GEMM: C[M=8192][N=1024] = A[8192][1024](bf16) @ Bt[1024][1024]^T(bf16) + bias
// MODE 0: store bf16 to head layout [B,H,S,64]
// MODE 1: store fp32 row-major [M][N] (final output projection)
template <int MODE>
__global__ __launch_bounds__(256) void gemm_bt(const unsigned short* __restrict__ A,
                                               const unsigned short* __restrict__ Bt,
                                               const float* __restrict__ bias,
                                               void* __restrict__ Cout) {
    __shared__ unsigned short As[128 * 32];
    __shared__ unsigned short Bs[128 * 32];
    const int tid = threadIdx.x, wave = tid >> 6, lane = tid & 63;
    const int lq = lane & 15, quad = lane >> 4;
    const int bm = blockIdx.x * 128, bn = blockIdx.y * 128;
    const int wm = (wave & 1) * 64, wn = (wave >> 1) * 64;
    const int K = 1024;

    f32x4 acc[4][4];
#pragma unroll
    for (int mi = 0; mi < 4; mi++)
#pragma unroll
        for (int ni = 0; ni < 4; ni++) acc[mi][ni] = f32x4{0.f, 0.f, 0.f, 0.f};

    for (int k0 = 0; k0 < K; k0 += 32) {
        __syncthreads();
#pragma unroll
        for (int c0 = 0; c0 < 2; c0++) {
            int c = c0 * 256 + tid;
            int row = c >> 2, k8 = (c & 3) * 8;
            *(int4*)(As + row * 32 + k8) =
                *(const int4*)(A + (size_t)(bm + row) * K + k0 + k8);
            *(int4*)(Bs + row * 32 + k8) =
                *(const int4*)(Bt + (size_t)(bn + row) * K + k0 + k8);
        }
        __syncthreads();

        short8 af[4], bfr[4];
#pragma unroll
        for (int mi = 0; mi < 4; mi++)
            af[mi] = *(const short8*)(As + (wm + mi * 16 + lq) * 32 + quad * 8);
#pragma unroll
        for (int ni = 0; ni < 4; ni++)
            bfr[ni] = *(const short8*)(Bs + (wn + ni * 16 + lq) * 32 + quad * 8);
#pragma unroll
        for (int mi = 0; mi < 4; mi++)
#pragma unroll
            for (int ni = 0; ni < 4; ni++)
                acc[mi][ni] = mfma16(af[mi], bfr[ni], acc[mi][ni]);
    }

    // Epilogue: D[row = quad*4 + r][col = lane&15] per 16x16 tile (m89-verified)
#pragma unroll
    for (int mi = 0; mi < 4; mi++)
#pragma unroll
        for (int ni = 0; ni < 4; ni++) {
            int col = bn + wn + ni * 16 + lq;
            float bv = bias[col];
#pragma unroll
            for (int r = 0; r < 4; r++) {
                int row = bm + wm + mi * 16 + quad * 4 + r;
                float val = acc[mi][ni][r] + bv;
                if (MODE == 0) {
                    int b = row >> 11, s = row & 2047;
                    int h = col >> 6, d = col & 63;
                    ((unsigned short*)Cout)[(((size_t)(b * SH + h) * SS + s) * DPT) + d] =
                        f2bf(val);
                } else {
                    ((float*)Cout)[(size_t)row * SD + col] = val;
                }
            }
        }
}

// ---------------------------------------------------------------------------
// Fused attention: per (b,h, 128-row q tile). Two-pass online softmax.
// Round-1 changes: bit-packed mask (L2-resident), register-prefetched K/V
// staging (HBM latency hidden under compute), Q fragments hoisted to
// registers (qs LDS tile removed entirely).
__global__ __launch_bounds__(256, 2) void attn_k(const unsigned short* __restrict__ qp,
                                                 const unsigned short* __restrict__ kp,
                                                 const unsigned short* __restrict__ vt,
                                                 const unsigned int* __restrict__ mbits,
                                                 float* __restrict__ attn,
                                                 unsigned short* __restrict__ rep) {
    __shared__ unsigned short ks[128 * 72];   // stride 72 -> 2-way-max banks
    __shared__ unsigned short vs[64 * 136];   // vt tile [d][s]
    __shared__ unsigned short ps[4 * 32 * 40];  // per-wave P-chunk (C->A layout xform)

    const int tid = threadIdx.x, wave = tid >> 6, lane = tid & 63;
    const int lq = lane & 15, quad = lane >> 4;
    const int qt = blockIdx.x, bh = blockIdx.y, b = bh >> 4, h = bh & 15;

    const unsigned short* qbase = qp + ((size_t)bh * SS + qt * 128) * DPT;
    const unsigned short* kbase = kp + (size_t)bh * SS * DPT;
    const unsigned short* vbase = vt + (size_t)bh * DPT * SS;
    // 2048 bits = 64 words per mask row
    const unsigned int* mrow = mbits + ((size_t)b * SS + qt * 128) * 64;
    float* abase = attn + ((size_t)bh * SS + qt * 128) * SS;

    // Q fragments straight from global: rows this wave owns, held in regs for
    // both passes (Q tile is only 16 KB/block, read once).
    short8 af[2][2];
#pragma unroll
    for (int mi = 0; mi < 2; mi++)
#pragma unroll
        for (int kk = 0; kk < 2; kk++)
            af[mi][kk] = *(const short8*)(qbase +
                (size_t)(wave * 32 + mi * 16 + lq) * DPT + kk * 32 + quad * 8);

    float m_run[8], l_run[8];
#pragma unroll
    for (int i = 0; i < 8; i++) { m_run[i] = -INFINITY; l_run[i] = 0.f; }

    // ---------------- PASS 1: running max / sum ----------------
    int4 kpre[4];
#pragma unroll
    for (int c0 = 0; c0 < 4; c0++) {
        int c = c0 * 256 + tid, row = c >> 3, k8 = (c & 7) * 8;
        kpre[c0] = *(const int4*)(kbase + (size_t)row * DPT + k8);
    }

    for (int kt = 0; kt < 16; ++kt) {
        __syncthreads();
#pragma unroll
        for (int c0 = 0; c0 < 4; c0++) {
            int c = c0 * 256 + tid, row = c >> 3, k8 = (c & 7) * 8;
            *(int4*)(ks + row * 72 + k8) = kpre[c0];
        }
        if (kt < 15) {
#pragma unroll
            for (int c0 = 0; c0 < 4; c0++) {
                int c = c0 * 256 + tid, row = c >> 3, k8 = (c & 7) * 8;
                kpre[c0] =
                    *(const int4*)(kbase + (size_t)((kt + 1) * 128 + row) * DPT + k8);
            }
        }
        __syncthreads();

        // mask bits for this tile: one uint4 (128 bits) per owned row; lanes in
        // a quad broadcast the same word (L1/L2-resident, 2 MB total).
        uint4 mw[2][4];
#pragma unroll
        for (int mi = 0; mi < 2; mi++)
#pragma unroll
            for (int r = 0; r < 4; r++)
                mw[mi][r] = *(const uint4*)(mrow +
                    (size_t)(wave * 32 + mi * 16 + quad * 4 + r) * 64 + kt * 4);

        f32x4 sc[2][8];
#pragma unroll
        for (int mi = 0; mi < 2; mi++)
#pragma unroll
            for (int ni = 0; ni < 8; ni++) sc[mi][ni] = f32x4{0.f, 0.f, 0.f, 0.f};
#pragma unroll
        for (int ni = 0; ni < 8; ni++)
#pragma unroll
            for (int kk = 0; kk < 2; kk++) {
                short8 bfr = *(const short8*)(ks + (ni * 16 + lq) * 72 + kk * 32 + quad * 8);
#pragma unroll
                for (int mi = 0; mi < 2; mi++)
                    sc[mi][ni] = mfma16(af[mi][kk], bfr, sc[mi][ni]);
            }
        // scale + mask: s*0.125 + (bit ? -1e9 : 0)  (identical fp32 math)
#pragma unroll
        for (int mi = 0; mi < 2; mi++)
#pragma unroll
            for (int ni = 0; ni < 8; ni++)
#pragma unroll
                for (int r = 0; r < 4; r++) {
                    unsigned wsel = (ni >> 1) == 0 ? mw[mi][r].x
                                  : (ni >> 1) == 1 ? mw[mi][r].y
                                  : (ni >> 1) == 2 ? mw[mi][r].z
                                                   : mw[mi][r].w;
                    float pen = ((wsel >> (((ni & 1) << 4) + lq)) & 1u) ? -1e9f : 0.f;
                    sc[mi][ni][r] = sc[mi][ni][r] * 0.125f + pen;
                }
        // online softmax state update (rows live in this lane's quad)
#pragma unroll
        for (int mi = 0; mi < 2; mi++)
#pragma unroll
            for (int r = 0; r < 4; r++) {
                float tmax = sc[mi][0][r];
#pragma unroll
                for (int ni = 1; ni < 8; ni++) tmax = fmaxf(tmax, sc[mi][ni][r]);
#pragma unroll
                for (int off = 1; off < 16; off <<= 1)
                    tmax = fmaxf(tmax, __shfl_xor(tmax, off));
                const int si = mi * 4 + r;
                float mn = fmaxf(m_run[si], tmax);
                float psum = 0.f;
#pragma unroll
                for (int ni = 0; ni < 8; ni++) psum += __expf(sc[mi][ni][r] - mn);
#pragma unroll
                for (int off = 1; off < 16; off <<= 1) psum += __shfl_xor(psum, off);
                l_run[si] = l_run[si] * __expf(m_run[si] - mn) + psum;
                m_run[si] = mn;
            }
    }

    float linv[8];
#pragma unroll
    for (int i = 0; i < 8; i++) linv[i] = 1.f / l_run[i];

    f32x4 racc[2][4];
#pragma unroll
    for (int mi = 0; mi < 2; mi++)
#pragma unroll
        for (int di = 0; di < 4; di++) racc[mi][di] = f32x4{0.f, 0.f, 0.f, 0.f};

    // ---------------- PASS 2: recompute, write attn, P@V ----------------
    int4 vpre[4];
#pragma unroll
    for (int c0 = 0; c0 < 4; c0++) {
        int c = c0 * 256 + tid, row = c >> 3, k8 = (c & 7) * 8;
        kpre[c0] = *(const int4*)(kbase + (size_t)row * DPT + k8);
    }
#pragma unroll
    for (int c0 = 0; c0 < 4; c0++) {
        int c = c0 * 256 + tid, row = c >> 4, s8 = (c & 15) * 8;
        vpre[c0] = *(const int4*)(vbase + (size_t)row * SS + s8);
    }

    for (int kt = 0; kt < 16; ++kt) {
        __syncthreads();
#pragma unroll
        for (int c0 = 0; c0 < 4; c0++) {
            int c = c0 * 256 + tid;
            { int row = c >> 3, k8 = (c & 7) * 8;
              *(int4*)(ks + row * 72 + k8) = kpre[c0]; }
            { int row = c >> 4, s8 = (c & 15) * 8;
              *(int4*)(vs + row * 136 + s8) = vpre[c0]; }
        }
        if (kt < 15) {
#pragma unroll
            for (int c0 = 0; c0 < 4; c0++) {
                int c = c0 * 256 + tid;
                { int row = c >> 3, k8 = (c & 7) * 8;
                  kpre[c0] = *(const int4*)(kbase +
                      (size_t)((kt + 1) * 128 + row) * DPT + k8); }
                { int row = c >> 4, s8 = (c & 15) * 8;
                  vpre[c0] = *(const int4*)(vbase +
                      (size_t)row * SS + (kt + 1) * 128 + s8); }
            }
        }
        __syncthreads();

        uint4 mw[2][4];
#pragma unroll
        for (int mi = 0; mi < 2; mi++)
#pragma unroll
            for (int r = 0; r < 4; r++)
                mw[mi][r] = *(const uint4*)(mrow +
                    (size_t)(wave * 32 + mi * 16 + quad * 4 + r) * 64 + kt * 4);

        f32x4 sc[2][8];
#pragma unroll
        for (int mi = 0; mi < 2; mi++)
#pragma unroll
            for (int ni = 0; ni < 8; ni++) sc[mi][ni] = f32x4{0.f, 0.f, 0.f, 0.f};
#pragma unroll
        for (int ni = 0; ni < 8; ni++)
#pragma unroll
            for (int kk = 0; kk < 2; kk++) {
                short8 bfr = *(const short8*)(ks + (ni * 16 + lq) * 72 + kk * 32 + quad * 8);
#pragma unroll
                for (int mi = 0; mi < 2; mi++)
                    sc[mi][ni] = mfma16(af[mi][kk], bfr, sc[mi][ni]);
            }
#pragma unroll
        for (int mi = 0; mi < 2; mi++)
#pragma unroll
            for (int ni = 0; ni < 8; ni++)
#pragma unroll
                for (int r = 0; r < 4; r++) {
                    unsigned wsel = (ni >> 1) == 0 ? mw[mi][r].x
                                  : (ni >> 1) == 1 ? mw[mi][r].y
                                  : (ni >> 1) == 2 ? mw[mi][r].z
                                                   : mw[mi][r].w;
                    float pen = ((wsel >> (((ni & 1) << 4) + lq)) & 1u) ? -1e9f : 0.f;
                    sc[mi][ni][r] = sc[mi][ni][r] * 0.125f + pen;
                }

        unsigned short* pc = ps + wave * 1280;  // [32][40] per wave
#pragma unroll
        for (int kc = 0; kc < 4; kc++) {
#pragma unroll
            for (int mi = 0; mi < 2; mi++)
#pragma unroll
                for (int nn = 0; nn < 2; nn++) {
                    int ni = kc * 2 + nn;
#pragma unroll
                    for (int r = 0; r < 4; r++) {
                        float p = __expf(sc[mi][ni][r] - m_run[mi * 4 + r]) *
                                  linv[mi * 4 + r];
                        abase[(size_t)(wave * 32 + mi * 16 + quad * 4 + r) * SS +
                              kt * 128 + ni * 16 + lq] = p;
                        // C/D layout (row=quad*4+r, col=lq) -> [m][k] in LDS
                        pc[(mi * 16 + quad * 4 + r) * 40 + nn * 16 + lq] = f2bf(p);
                    }
                }
            asm volatile("s_waitcnt lgkmcnt(0)" ::: "memory");
#pragma unroll
            for (int mi = 0; mi < 2; mi++) {
                // A-operand layout: A[m=lane&15][k=quad*8+j] (m120-verified)
                short8 a = *(const short8*)(pc + (mi * 16 + lq) * 40 + quad * 8);
#pragma unroll
                for (int di = 0; di < 4; di++) {
                    short8 v = *(const short8*)(vs + (di * 16 + lq) * 136 +
                                                kc * 32 + quad * 8);
                    racc[mi][di] = mfma16(a, v, racc[mi][di]);
                }
            }
            asm volatile("s_waitcnt lgkmcnt(0)" ::: "memory");
        }
    }

    // write rep to concat layout [B,S,H*64] bf16
#pragma unroll
    for (int mi = 0; mi < 2; mi++)
#pragma unroll
        for (int di = 0; di < 4; di++)
#pragma unroll
            for (int r = 0; r < 4; r++) {
                int s = qt * 128 + wave * 32 + mi * 16 + quad * 4 + r;
                int d = di * 16 + lq;
                rep[((size_t)b * SS + s) * SD + h * DPT + d] = f2bf(racc[mi][di][r]);
            }
}

// ---------------------------------------------------------------------------
extern "C" void kernel_launch(void* const* d_in, const int* in_sizes, int n_in,
                              void* d_out, int out_size, void* d_ws, size_t ws_size,
                              hipStream_t stream) {
    const float* Q = (const float*)d_in[0];
    const float* K = (const float*)d_in[1];
    const float* V = (const float*)d_in[2];
    const float* Mask = (const float*)d_in[3];
    const float* Wq = (const float*)d_in[4];  const float* bq = (const float*)d_in[5];
    const float* Wk = (const float*)d_in[6];  const float* bk = (const float*)d_in[7];
    const float* Wv = (const float*)d_in[8];  const float* bv = (const float*)d_in[9];
    const float* Wo = (const float*)d_in[10]; const float* bo = (const float*)d_in[11];

    float* out = (float*)d_out;
    float* attn = out + (size_t)SB * SS * SD;  // out first, then attn

    // workspace layout (bf16 elements); total ~104 MB
    unsigned short* ws = (unsigned short*)d_ws;
    const size_t PROJ = (size_t)SB * SS * SD;  // 8,388,608
    const size_t WSZ = (size_t)SD * SD;        // 1,048,576
    unsigned short* Qb  = ws;                 // later reused as rep
    unsigned short* Kb  = ws + PROJ;          // later reused as vt
    unsigned short* Vb  = ws + 2 * PROJ;      // later reused as mask bits
    unsigned short* qph = ws + 3 * PROJ;      // q head layout
    unsigned short* kph = ws + 4 * PROJ;
    unsigned short* vph = ws + 5 * PROJ;
    unsigned short* Wtq = ws + 6 * PROJ;
    unsigned short* Wtk = Wtq + WSZ;
    unsigned short* Wtv = Wtk + WSZ;
    unsigned short* Wto = Wtv + WSZ;
    unsigned short* vtb = Kb;   // alias: Kb dead after k projection
    unsigned short* repb = Qb;  // alias: Qb dead after q projection
    unsigned int* mbitsb = (unsigned int*)Vb;  // alias: Vb dead after v projection (2 MB)

    cast_k<<<8192, 256, 0, stream>>>(Q, Qb);
    cast_k<<<8192, 256, 0, stream>>>(K, Kb);
    cast_k<<<8192, 256, 0, stream>>>(V, Vb);
    wtrans_k<<<dim3(32, 32), 256, 0, stream>>>(Wq, Wtq);
    wtrans_k<<<dim3(32, 32), 256, 0, stream>>>(Wk, Wtk);
    wtrans_k<<<dim3(32, 32), 256, 0, stream>>>(Wv, Wtv);
    wtrans_k<<<dim3(32, 32), 256, 0, stream>>>(Wo, Wto);

    gemm_bt<0><<<dim3(64, 8), 256, 0, stream>>>(Qb, Wtq, bq, qph);
    gemm_bt<0><<<dim3(64, 8), 256, 0, stream>>>(Kb, Wtk, bk, kph);
    gemm_bt<0><<<dim3(64, 8), 256, 0, stream>>>(Vb, Wtv, bv, vph);

    // mask bit-pack AFTER the V projection (mbitsb aliases Vb)
    maskbits_k<<<65536, 256, 0, stream>>>(Mask, mbitsb);

    vtrans_k<<<dim3(2, 64, 64), 256, 0, stream>>>(vph, vtb);

    attn_k<<<dim3(16, 64), 256, 0, stream>>>(qph, kph, vtb, mbitsb, attn, repb);

    gemm_bt<1><<<dim3(64, 8), 256, 0, stream>>>(repb, Wto, bo, out);
}